// Round 1
// baseline (1493.154 us; speedup 1.0000x reference)
//
#include <hip/hip_runtime.h>
#include <math.h>

#define N_NODES 50000
#define N_EDGES 600000
#define F 128
#define NT 4
#define KTOT (F * (NT + 1))   // 640

// ---------------- build combined weights: Wcat[640][128], bavg[2][128] ----------------
__global__ __launch_bounds__(256) void build_w(
    const float* __restrict__ Ws1, const float* __restrict__ Wn1, const float* __restrict__ b1,
    const float* __restrict__ Ws2, const float* __restrict__ Wn2, const float* __restrict__ b2,
    float* __restrict__ Wc1, float* __restrict__ Wc2, float* __restrict__ bavg)
{
    int idx = blockIdx.x * 256 + threadIdx.x;
    const int total = KTOT * F;  // 81920
    if (idx < 2 * total) {
        int l = idx / total;
        int rem = idx - l * total;
        int r = rem / F;
        int j = rem - r * F;
        const float* Wsl = l ? Ws2 : Ws1;
        const float* Wnl = l ? Wn2 : Wn1;
        float* out = l ? Wc2 : Wc1;
        int p = r >> 7;          // 0 => self-avg plane, 1..4 => neigh planes
        int kk = r & (F - 1);
        float v;
        if (p == 0) {
            v = 0.25f * (Wsl[(0 * F + kk) * F + j] + Wsl[(1 * F + kk) * F + j] +
                         Wsl[(2 * F + kk) * F + j] + Wsl[(3 * F + kk) * F + j]);
        } else {
            v = 0.25f * Wnl[((p - 1) * F + kk) * F + j];
        }
        out[(size_t)r * F + j] = v;
    } else {
        int k = idx - 2 * total;
        if (k < 2 * F) {
            int l = k >> 7;
            int j = k & (F - 1);
            const float* bl = l ? b2 : b1;
            bavg[k] = 0.25f * (bl[j] + bl[F + j] + bl[2 * F + j] + bl[3 * F + j]);
        }
    }
}

// ---------------- edge scatter: one wave per edge ----------------
__global__ __launch_bounds__(256) void scatter_edges(
    const float* __restrict__ H, const int* __restrict__ srcA,
    const int* __restrict__ dstA, const int* __restrict__ typA,
    float* __restrict__ agg, float* __restrict__ cnt)
{
    int e = blockIdx.x * 4 + (threadIdx.x >> 6);
    int lane = threadIdx.x & 63;
    if (e >= N_EDGES) return;
    int s = srcA[e];
    int d = dstA[e];
    int t = typA[e];
    float2 v = ((const float2*)(H + (size_t)s * F))[lane];
    float* op = agg + ((size_t)t * N_NODES + d) * F + lane * 2;
    atomicAdd(op, v.x);
    atomicAdd(op + 1, v.y);
    if (lane == 0) atomicAdd(cnt + t * N_NODES + d, 1.0f);
}

// ---------------- cnt -> 1/max(cnt,1) in place ----------------
__global__ __launch_bounds__(256) void make_inv(float* __restrict__ cnt)
{
    int i = blockIdx.x * 256 + threadIdx.x;
    if (i < NT * N_NODES) cnt[i] = 1.0f / fmaxf(cnt[i], 1.0f);
}

// ---------------- fused virtual-GEMM [N,640]x[640,128] (+bias, +opt norm/relu) ------
// block: 128 threads = 2 waves, tile 64 nodes x 128 cols, 8x8 per-thread regs
__global__ __launch_bounds__(128) void gemm_fused(
    const float* __restrict__ X,     // [N,F] dense input rows (plane 0)
    const float* __restrict__ agg,   // [NT,N,F]
    const float* __restrict__ inv,   // [NT,N]  (1/max(cnt,1))
    const float* __restrict__ W,     // [KTOT,F]
    const float* __restrict__ bias,  // [F]
    float* __restrict__ out,         // [N,F]
    int doNormRelu)
{
    __shared__ float As[32][68];     // A chunk transposed: As[k][m]
    __shared__ float Ws[32][132];    // W chunk: Ws[k][j]
    __shared__ float red[64][17];    // row-norm reduction

    const int tid = threadIdx.x;
    const int tx = tid & 15;         // col group: 8 cols each
    const int ty = tid >> 4;         // row group: 8 rows each
    const int c0 = tx * 8;
    const int r0 = ty * 8;
    const int nodeBase = blockIdx.x * 64;

    float acc[8][8];
#pragma unroll
    for (int i = 0; i < 8; ++i)
#pragma unroll
        for (int j = 0; j < 8; ++j) acc[i][j] = 0.0f;

    const int mA = tid & 15;         // staging: row within 16-row pass
    const int cA = (tid >> 4) * 4;   // staging: col base (0,4,...,28)
    const int jW = (tid & 31) * 4;
    const int kW = tid >> 5;         // 0..3

    for (int kc = 0; kc < KTOT / 32; ++kc) {
        const int k0 = kc * 32;
        const int p = k0 >> 7;       // source plane
        const int kk0 = k0 & (F - 1);

        // stage A: 64 rows x 32 cols, scaled, transposed into As[k][m]
#pragma unroll
        for (int it = 0; it < 4; ++it) {
            int m = mA + it * 16;
            int n = nodeBase + m;
            int nc = n < N_NODES ? n : N_NODES - 1;   // clamp; store is guarded
            const float* srcp;
            float scale;
            if (p == 0) {
                srcp = X + (size_t)nc * F + kk0;
                scale = 1.0f;
            } else {
                int pl = p - 1;
                srcp = agg + ((size_t)pl * N_NODES + nc) * F + kk0;
                scale = inv[pl * N_NODES + nc];
            }
            float4 v = *(const float4*)(srcp + cA);
            As[cA + 0][m] = v.x * scale;
            As[cA + 1][m] = v.y * scale;
            As[cA + 2][m] = v.z * scale;
            As[cA + 3][m] = v.w * scale;
        }
        // stage W: 32 x 128
#pragma unroll
        for (int it = 0; it < 8; ++it) {
            int kk = kW + it * 4;
            *(float4*)&Ws[kk][jW] = *(const float4*)(W + (size_t)(k0 + kk) * F + jW);
        }
        __syncthreads();

#pragma unroll 8
        for (int kk = 0; kk < 32; ++kk) {
            float4 a0 = *(const float4*)&As[kk][r0];
            float4 a1 = *(const float4*)&As[kk][r0 + 4];
            float4 w0 = *(const float4*)&Ws[kk][c0];
            float4 w1 = *(const float4*)&Ws[kk][c0 + 4];
            float a[8] = {a0.x, a0.y, a0.z, a0.w, a1.x, a1.y, a1.z, a1.w};
            float w[8] = {w0.x, w0.y, w0.z, w0.w, w1.x, w1.y, w1.z, w1.w};
#pragma unroll
            for (int i = 0; i < 8; ++i)
#pragma unroll
                for (int j = 0; j < 8; ++j)
                    acc[i][j] += a[i] * w[j];
        }
        __syncthreads();
    }

    // bias (before normalize, per reference)
#pragma unroll
    for (int j = 0; j < 8; ++j) {
        float b = bias[c0 + j];
#pragma unroll
        for (int i = 0; i < 8; ++i) acc[i][j] += b;
    }

    if (doNormRelu) {
        // row L2 norms: block owns the full 128-col row
#pragma unroll
        for (int i = 0; i < 8; ++i) {
            float s = 0.0f;
#pragma unroll
            for (int j = 0; j < 8; ++j) s += acc[i][j] * acc[i][j];
            red[r0 + i][tx] = s;
        }
        __syncthreads();
        if (tid < 64) {
            float s = 0.0f;
#pragma unroll
            for (int t = 0; t < 16; ++t) s += red[tid][t];
            float nrm = sqrtf(s);
            red[tid][16] = 1.0f / fmaxf(nrm, 1e-12f);
        }
        __syncthreads();
#pragma unroll
        for (int i = 0; i < 8; ++i) {
            float sc = red[r0 + i][16];
#pragma unroll
            for (int j = 0; j < 8; ++j) acc[i][j] = fmaxf(acc[i][j] * sc, 0.0f);
        }
    }

    // store
#pragma unroll
    for (int i = 0; i < 8; ++i) {
        int n = nodeBase + r0 + i;
        if (n < N_NODES) {
            float4 v0 = make_float4(acc[i][0], acc[i][1], acc[i][2], acc[i][3]);
            float4 v1 = make_float4(acc[i][4], acc[i][5], acc[i][6], acc[i][7]);
            *(float4*)(out + (size_t)n * F + c0) = v0;
            *(float4*)(out + (size_t)n * F + c0 + 4) = v1;
        }
    }
}

extern "C" void kernel_launch(void* const* d_in, const int* in_sizes, int n_in,
                              void* d_out, int out_size, void* d_ws, size_t ws_size,
                              hipStream_t stream)
{
    const float* x   = (const float*)d_in[0];
    const float* Ws1 = (const float*)d_in[1];
    const float* Wn1 = (const float*)d_in[2];
    const float* b1  = (const float*)d_in[3];
    const float* Ws2 = (const float*)d_in[4];
    const float* Wn2 = (const float*)d_in[5];
    const float* b2  = (const float*)d_in[6];
    const int* edge_index = (const int*)d_in[7];
    const int* edge_type  = (const int*)d_in[8];
    // d_in[9..12] (beat/measure nodes/edges) unused by the reference path

    const int* srcA = edge_index;
    const int* dstA = edge_index + N_EDGES;

    // workspace layout (floats)
    float* ws   = (float*)d_ws;
    float* agg  = ws;                                        // NT*N*F = 25,600,000
    float* cnt  = agg + (size_t)NT * N_NODES * F;            // NT*N   =    200,000
    float* h1   = cnt + (size_t)NT * N_NODES;                // N*F    =  6,400,000
    float* Wc1  = h1 + (size_t)N_NODES * F;                  // 81,920
    float* Wc2  = Wc1 + (size_t)KTOT * F;                    // 81,920
    float* bavg = Wc2 + (size_t)KTOT * F;                    // 256

    const size_t aggCntBytes = ((size_t)NT * N_NODES * F + (size_t)NT * N_NODES) * sizeof(float);

    // build concatenated weights + averaged bias
    {
        int totalThreads = 2 * KTOT * F + 2 * F;             // 164096
        hipLaunchKernelGGL(build_w, dim3((totalThreads + 255) / 256), dim3(256), 0, stream,
                           Ws1, Wn1, b1, Ws2, Wn2, b2, Wc1, Wc2, bavg);
    }

    // ---------- layer 1 ----------
    hipMemsetAsync(agg, 0, aggCntBytes, stream);
    hipLaunchKernelGGL(scatter_edges, dim3(N_EDGES / 4), dim3(256), 0, stream,
                       x, srcA, dstA, edge_type, agg, cnt);
    hipLaunchKernelGGL(make_inv, dim3((NT * N_NODES + 255) / 256), dim3(256), 0, stream, cnt);
    hipLaunchKernelGGL(gemm_fused, dim3((N_NODES + 63) / 64), dim3(128), 0, stream,
                       x, agg, cnt, Wc1, bavg, h1, 1);

    // ---------- layer 2 ----------
    hipMemsetAsync(agg, 0, aggCntBytes, stream);
    hipLaunchKernelGGL(scatter_edges, dim3(N_EDGES / 4), dim3(256), 0, stream,
                       h1, srcA, dstA, edge_type, agg, cnt);
    hipLaunchKernelGGL(make_inv, dim3((NT * N_NODES + 255) / 256), dim3(256), 0, stream, cnt);
    hipLaunchKernelGGL(gemm_fused, dim3((N_NODES + 63) / 64), dim3(128), 0, stream,
                       h1, agg, cnt, Wc2, bavg + F, (float*)d_out, 0);
}

// Round 2
// 660.132 us; speedup vs baseline: 2.2619x; 2.2619x over previous
//
#include <hip/hip_runtime.h>
#include <math.h>

#define N_NODES 50000
#define N_EDGES 600000
#define F 128
#define NT 4
#define KTOT (F * (NT + 1))   // 640
#define N_SEG (NT * N_NODES)  // 200000
#define SCAN_BLK 196          // ceil(N_SEG / 1024)

// ---------------- build combined weights: Wcat[640][128], bavg[2][128] ----------------
__global__ __launch_bounds__(256) void build_w(
    const float* __restrict__ Ws1, const float* __restrict__ Wn1, const float* __restrict__ b1,
    const float* __restrict__ Ws2, const float* __restrict__ Wn2, const float* __restrict__ b2,
    float* __restrict__ Wc1, float* __restrict__ Wc2, float* __restrict__ bavg)
{
    int idx = blockIdx.x * 256 + threadIdx.x;
    const int total = KTOT * F;  // 81920
    if (idx < 2 * total) {
        int l = idx / total;
        int rem = idx - l * total;
        int r = rem / F;
        int j = rem - r * F;
        const float* Wsl = l ? Ws2 : Ws1;
        const float* Wnl = l ? Wn2 : Wn1;
        float* out = l ? Wc2 : Wc1;
        int p = r >> 7;          // 0 => self-avg plane, 1..4 => neigh planes
        int kk = r & (F - 1);
        float v;
        if (p == 0) {
            v = 0.25f * (Wsl[(0 * F + kk) * F + j] + Wsl[(1 * F + kk) * F + j] +
                         Wsl[(2 * F + kk) * F + j] + Wsl[(3 * F + kk) * F + j]);
        } else {
            v = 0.25f * Wnl[((p - 1) * F + kk) * F + j];
        }
        out[(size_t)r * F + j] = v;
    } else {
        int k = idx - 2 * total;
        if (k < 2 * F) {
            int l = k >> 7;
            int j = k & (F - 1);
            const float* bl = l ? b2 : b1;
            bavg[k] = 0.25f * (bl[j] + bl[F + j] + bl[2 * F + j] + bl[3 * F + j]);
        }
    }
}

// ---------------- CSR build: histogram over (type,dst) buckets ----------------
__global__ __launch_bounds__(256) void hist_kernel(
    const int* __restrict__ dstA, const int* __restrict__ typA, int* __restrict__ counts)
{
    int e = blockIdx.x * 256 + threadIdx.x;
    if (e < N_EDGES) atomicAdd(&counts[typA[e] * N_NODES + dstA[e]], 1);
}

// scan1: per-block (1024 elems) exclusive scan in place; block totals to bsum
__global__ __launch_bounds__(256) void scan1(int* __restrict__ counts, int* __restrict__ bsum)
{
    __shared__ int sh[256];
    int t = threadIdx.x;
    int base = blockIdx.x * 1024 + t * 4;
    int v[4];
    int tot = 0;
#pragma unroll
    for (int j = 0; j < 4; ++j) {
        int i = base + j;
        v[j] = (i < N_SEG) ? counts[i] : 0;
        tot += v[j];
    }
    sh[t] = tot;
    __syncthreads();
    for (int ofs = 1; ofs < 256; ofs <<= 1) {
        int add = (t >= ofs) ? sh[t - ofs] : 0;
        __syncthreads();
        sh[t] += add;
        __syncthreads();
    }
    int excl = (t > 0) ? sh[t - 1] : 0;
    if (t == 255) bsum[blockIdx.x] = sh[255];
#pragma unroll
    for (int j = 0; j < 4; ++j) {
        int i = base + j;
        if (i < N_SEG) counts[i] = excl;
        excl += v[j];
    }
}

// scan2: exclusive scan of block sums (single block)
__global__ __launch_bounds__(256) void scan2(int* __restrict__ bsum)
{
    __shared__ int sh[256];
    int t = threadIdx.x;
    sh[t] = (t < SCAN_BLK) ? bsum[t] : 0;
    __syncthreads();
    for (int ofs = 1; ofs < 256; ofs <<= 1) {
        int add = (t >= ofs) ? sh[t - ofs] : 0;
        __syncthreads();
        sh[t] += add;
        __syncthreads();
    }
    int excl = (t > 0) ? sh[t - 1] : 0;
    if (t < SCAN_BLK) bsum[t] = excl;
}

// scan3: finalize global offsets; duplicate into cursor for the permute pass
__global__ __launch_bounds__(256) void scan3(
    const int* __restrict__ counts, const int* __restrict__ bsum,
    int* __restrict__ off, int* __restrict__ cursor)
{
    int i = blockIdx.x * 256 + threadIdx.x;
    if (i < N_SEG) {
        int v = counts[i] + bsum[i >> 10];
        off[i] = v;
        cursor[i] = v;
    }
}

// permute: place each edge's src id into its bucket slot
// (after this kernel, cursor[seg] == segment end)
__global__ __launch_bounds__(256) void permute_kernel(
    const int* __restrict__ srcA, const int* __restrict__ dstA, const int* __restrict__ typA,
    int* __restrict__ cursor, int* __restrict__ perm)
{
    int e = blockIdx.x * 256 + threadIdx.x;
    if (e < N_EDGES) {
        int pos = atomicAdd(&cursor[typA[e] * N_NODES + dstA[e]], 1);
        perm[pos] = srcA[e];
    }
}

// ---------------- gather-aggregate: one wave per (type,node) segment ----------------
// writes agg pre-scaled by 1/max(cnt,1); writes zeros for empty segments (no memset needed)
__global__ __launch_bounds__(256) void gather_agg(
    const float* __restrict__ H, const int* __restrict__ perm,
    const int* __restrict__ off, const int* __restrict__ segend,
    float* __restrict__ agg)
{
    int seg = blockIdx.x * 4 + (threadIdx.x >> 6);
    int lane = threadIdx.x & 63;
    if (seg >= N_SEG) return;
    int start = off[seg];
    int end = segend[seg];
    float sx = 0.0f, sy = 0.0f;
    for (int e = start; e < end; ++e) {
        int s = perm[e];
        float2 xv = ((const float2*)(H + (size_t)s * F))[lane];
        sx += xv.x;
        sy += xv.y;
    }
    float sc = 1.0f / fmaxf((float)(end - start), 1.0f);
    ((float2*)(agg + (size_t)seg * F))[lane] = make_float2(sx * sc, sy * sc);
}

// ---------------- fused virtual-GEMM [N,640]x[640,128] (+bias, +opt norm/relu) ------
// block: 128 threads = 2 waves, tile 64 nodes x 128 cols, 8x8 per-thread regs
__global__ __launch_bounds__(128) void gemm_fused(
    const float* __restrict__ X,     // [N,F] dense input rows (plane 0)
    const float* __restrict__ agg,   // [NT,N,F] pre-scaled means
    const float* __restrict__ W,     // [KTOT,F]
    const float* __restrict__ bias,  // [F]
    float* __restrict__ out,         // [N,F]
    int doNormRelu)
{
    __shared__ float As[32][68];     // A chunk transposed: As[k][m]
    __shared__ float Ws[32][132];    // W chunk: Ws[k][j]
    __shared__ float red[64][17];    // row-norm reduction

    const int tid = threadIdx.x;
    const int tx = tid & 15;         // col group: 8 cols each
    const int ty = tid >> 4;         // row group: 8 rows each
    const int c0 = tx * 8;
    const int r0 = ty * 8;
    const int nodeBase = blockIdx.x * 64;

    float acc[8][8];
#pragma unroll
    for (int i = 0; i < 8; ++i)
#pragma unroll
        for (int j = 0; j < 8; ++j) acc[i][j] = 0.0f;

    const int mA = tid & 15;         // staging: row within 16-row pass
    const int cA = (tid >> 4) * 4;   // staging: col base (0,4,...,28)
    const int jW = (tid & 31) * 4;
    const int kW = tid >> 5;         // 0..3

    for (int kc = 0; kc < KTOT / 32; ++kc) {
        const int k0 = kc * 32;
        const int p = k0 >> 7;       // source plane
        const int kk0 = k0 & (F - 1);

        // stage A: 64 rows x 32 cols, transposed into As[k][m]
#pragma unroll
        for (int it = 0; it < 4; ++it) {
            int m = mA + it * 16;
            int n = nodeBase + m;
            int nc = n < N_NODES ? n : N_NODES - 1;   // clamp; store is guarded
            const float* srcp;
            if (p == 0) {
                srcp = X + (size_t)nc * F + kk0;
            } else {
                srcp = agg + ((size_t)(p - 1) * N_NODES + nc) * F + kk0;
            }
            float4 v = *(const float4*)(srcp + cA);
            As[cA + 0][m] = v.x;
            As[cA + 1][m] = v.y;
            As[cA + 2][m] = v.z;
            As[cA + 3][m] = v.w;
        }
        // stage W: 32 x 128
#pragma unroll
        for (int it = 0; it < 8; ++it) {
            int kk = kW + it * 4;
            *(float4*)&Ws[kk][jW] = *(const float4*)(W + (size_t)(k0 + kk) * F + jW);
        }
        __syncthreads();

#pragma unroll 8
        for (int kk = 0; kk < 32; ++kk) {
            float4 a0 = *(const float4*)&As[kk][r0];
            float4 a1 = *(const float4*)&As[kk][r0 + 4];
            float4 w0 = *(const float4*)&Ws[kk][c0];
            float4 w1 = *(const float4*)&Ws[kk][c0 + 4];
            float a[8] = {a0.x, a0.y, a0.z, a0.w, a1.x, a1.y, a1.z, a1.w};
            float w[8] = {w0.x, w0.y, w0.z, w0.w, w1.x, w1.y, w1.z, w1.w};
#pragma unroll
            for (int i = 0; i < 8; ++i)
#pragma unroll
                for (int j = 0; j < 8; ++j)
                    acc[i][j] += a[i] * w[j];
        }
        __syncthreads();
    }

    // bias (before normalize, per reference)
#pragma unroll
    for (int j = 0; j < 8; ++j) {
        float b = bias[c0 + j];
#pragma unroll
        for (int i = 0; i < 8; ++i) acc[i][j] += b;
    }

    if (doNormRelu) {
        // row L2 norms: block owns the full 128-col row
#pragma unroll
        for (int i = 0; i < 8; ++i) {
            float s = 0.0f;
#pragma unroll
            for (int j = 0; j < 8; ++j) s += acc[i][j] * acc[i][j];
            red[r0 + i][tx] = s;
        }
        __syncthreads();
        if (tid < 64) {
            float s = 0.0f;
#pragma unroll
            for (int t = 0; t < 16; ++t) s += red[tid][t];
            float nrm = sqrtf(s);
            red[tid][16] = 1.0f / fmaxf(nrm, 1e-12f);
        }
        __syncthreads();
#pragma unroll
        for (int i = 0; i < 8; ++i) {
            float sc = red[r0 + i][16];
#pragma unroll
            for (int j = 0; j < 8; ++j) acc[i][j] = fmaxf(acc[i][j] * sc, 0.0f);
        }
    }

    // store
#pragma unroll
    for (int i = 0; i < 8; ++i) {
        int n = nodeBase + r0 + i;
        if (n < N_NODES) {
            float4 v0 = make_float4(acc[i][0], acc[i][1], acc[i][2], acc[i][3]);
            float4 v1 = make_float4(acc[i][4], acc[i][5], acc[i][6], acc[i][7]);
            *(float4*)(out + (size_t)n * F + c0) = v0;
            *(float4*)(out + (size_t)n * F + c0 + 4) = v1;
        }
    }
}

extern "C" void kernel_launch(void* const* d_in, const int* in_sizes, int n_in,
                              void* d_out, int out_size, void* d_ws, size_t ws_size,
                              hipStream_t stream)
{
    const float* x   = (const float*)d_in[0];
    const float* Ws1 = (const float*)d_in[1];
    const float* Wn1 = (const float*)d_in[2];
    const float* b1  = (const float*)d_in[3];
    const float* Ws2 = (const float*)d_in[4];
    const float* Wn2 = (const float*)d_in[5];
    const float* b2  = (const float*)d_in[6];
    const int* edge_index = (const int*)d_in[7];
    const int* edge_type  = (const int*)d_in[8];
    // d_in[9..12] (beat/measure nodes/edges) unused by the reference path

    const int* srcA = edge_index;
    const int* dstA = edge_index + N_EDGES;

    // workspace layout
    float* ws   = (float*)d_ws;
    float* agg  = ws;                                        // NT*N*F = 25,600,000 f
    float* h1   = agg + (size_t)NT * N_NODES * F;            // N*F    =  6,400,000 f
    float* Wc1  = h1 + (size_t)N_NODES * F;                  // 81,920 f
    float* Wc2  = Wc1 + (size_t)KTOT * F;                    // 81,920 f
    float* bavg = Wc2 + (size_t)KTOT * F;                    // 256 f
    int* counts = (int*)(bavg + 2 * F);                      // N_SEG
    int* off    = counts + N_SEG;                            // N_SEG
    int* cursor = off + N_SEG;                               // N_SEG
    int* bsum   = cursor + N_SEG;                            // 256
    int* perm   = bsum + 256;                                // N_EDGES

    // build concatenated weights + averaged bias
    {
        int totalThreads = 2 * KTOT * F + 2 * F;             // 164096
        hipLaunchKernelGGL(build_w, dim3((totalThreads + 255) / 256), dim3(256), 0, stream,
                           Ws1, Wn1, b1, Ws2, Wn2, b2, Wc1, Wc2, bavg);
    }

    // ---------- CSR build (once; shared by both layers) ----------
    hipMemsetAsync(counts, 0, (size_t)N_SEG * sizeof(int), stream);
    hipLaunchKernelGGL(hist_kernel, dim3((N_EDGES + 255) / 256), dim3(256), 0, stream,
                       dstA, edge_type, counts);
    hipLaunchKernelGGL(scan1, dim3(SCAN_BLK), dim3(256), 0, stream, counts, bsum);
    hipLaunchKernelGGL(scan2, dim3(1), dim3(256), 0, stream, bsum);
    hipLaunchKernelGGL(scan3, dim3((N_SEG + 255) / 256), dim3(256), 0, stream,
                       counts, bsum, off, cursor);
    hipLaunchKernelGGL(permute_kernel, dim3((N_EDGES + 255) / 256), dim3(256), 0, stream,
                       srcA, dstA, edge_type, cursor, perm);
    // now: off[seg] = start, cursor[seg] = end

    // ---------- layer 1 ----------
    hipLaunchKernelGGL(gather_agg, dim3(N_SEG / 4), dim3(256), 0, stream,
                       x, perm, off, cursor, agg);
    hipLaunchKernelGGL(gemm_fused, dim3((N_NODES + 63) / 64), dim3(128), 0, stream,
                       x, agg, Wc1, bavg, h1, 1);

    // ---------- layer 2 ----------
    hipLaunchKernelGGL(gather_agg, dim3(N_SEG / 4), dim3(256), 0, stream,
                       h1, perm, off, cursor, agg);
    hipLaunchKernelGGL(gemm_fused, dim3((N_NODES + 63) / 64), dim3(128), 0, stream,
                       h1, agg, Wc2, bavg + F, (float*)d_out, 0);
}

// Round 4
// 408.533 us; speedup vs baseline: 3.6549x; 1.6159x over previous
//
#include <hip/hip_runtime.h>
#include <math.h>

#define N_NODES 50000
#define N_EDGES 600000
#define F 128
#define NT 4
#define KTOT (F * (NT + 1))   // 640
#define N_SEG (NT * N_NODES)  // 200000
#define SCAN_BLK 196          // ceil(N_SEG / 1024)
#define NKT 20                // K chunks of 32
#define WELEM (NKT * 8 * 64 * 8)  // 81920 bf16 ELEMENTS per layer (10240 frags x 8)

typedef __attribute__((ext_vector_type(8))) short bf16x8;
typedef __attribute__((ext_vector_type(4))) float f32x4;

__device__ __forceinline__ unsigned short f2b(float f) {
    unsigned u = __float_as_uint(f);
    return (unsigned short)((u + 0x7FFFu + ((u >> 16) & 1u)) >> 16);
}
__device__ __forceinline__ float b2f(unsigned short h) {
    return __uint_as_float(((unsigned)h) << 16);
}

// ---- build pre-swizzled, hi/lo-split combined weights + averaged bias ----
// Whsw/Wlsw layout (per layer): frag index fi = (kt*8 + ct)*64 + lane, 8 bf16 each:
//   element j: Wcat[kt*32 + (lane>>4)*8 + j][ct*16 + (lane&15)]
__global__ __launch_bounds__(256) void build_w_mfma(
    const float* __restrict__ Ws1, const float* __restrict__ Wn1, const float* __restrict__ b1,
    const float* __restrict__ Ws2, const float* __restrict__ Wn2, const float* __restrict__ b2,
    unsigned short* __restrict__ Whsw, unsigned short* __restrict__ Wlsw,
    float* __restrict__ bavg)
{
    int idx = blockIdx.x * 256 + threadIdx.x;
    const int perLayer = NKT * 8 * 64;   // 10240 fragments
    if (idx < 2 * perLayer) {
        int l = idx >= perLayer;
        int rem = idx - l * perLayer;
        int lane = rem & 63;
        int ct = (rem >> 6) & 7;
        int kt = rem >> 9;
        const float* Wsl = l ? Ws2 : Ws1;
        const float* Wnl = l ? Wn2 : Wn1;
        // WELEM elements per layer; rem is a fragment index -> *8 elements
        unsigned short* oh = Whsw + (size_t)l * WELEM + (size_t)rem * 8;
        unsigned short* ol = Wlsw + (size_t)l * WELEM + (size_t)rem * 8;
        int c = ct * 16 + (lane & 15);
        int kbase = kt * 32 + (lane >> 4) * 8;
#pragma unroll
        for (int j = 0; j < 8; ++j) {
            int r = kbase + j;
            int p = r >> 7;
            int kk = r & (F - 1);
            float v;
            if (p == 0) {
                v = 0.25f * (Wsl[(0 * F + kk) * F + c] + Wsl[(1 * F + kk) * F + c] +
                             Wsl[(2 * F + kk) * F + c] + Wsl[(3 * F + kk) * F + c]);
            } else {
                v = 0.25f * Wnl[((p - 1) * F + kk) * F + c];
            }
            unsigned short h = f2b(v);
            oh[j] = h;
            ol[j] = f2b(v - b2f(h));
        }
    } else {
        int k = idx - 2 * perLayer;
        if (k < 2 * F) {
            int l = k >> 7;
            int j = k & (F - 1);
            const float* bl = l ? b2 : b1;
            bavg[k] = 0.25f * (bl[j] + bl[F + j] + bl[2 * F + j] + bl[3 * F + j]);
        }
    }
}

// ---------------- CSR build: histogram over (type,dst) buckets ----------------
__global__ __launch_bounds__(256) void hist_kernel(
    const int* __restrict__ dstA, const int* __restrict__ typA, int* __restrict__ counts)
{
    int e = blockIdx.x * 256 + threadIdx.x;
    if (e < N_EDGES) atomicAdd(&counts[typA[e] * N_NODES + dstA[e]], 1);
}

__global__ __launch_bounds__(256) void scan1(int* __restrict__ counts, int* __restrict__ bsum)
{
    __shared__ int sh[256];
    int t = threadIdx.x;
    int base = blockIdx.x * 1024 + t * 4;
    int v[4];
    int tot = 0;
#pragma unroll
    for (int j = 0; j < 4; ++j) {
        int i = base + j;
        v[j] = (i < N_SEG) ? counts[i] : 0;
        tot += v[j];
    }
    sh[t] = tot;
    __syncthreads();
    for (int ofs = 1; ofs < 256; ofs <<= 1) {
        int add = (t >= ofs) ? sh[t - ofs] : 0;
        __syncthreads();
        sh[t] += add;
        __syncthreads();
    }
    int excl = (t > 0) ? sh[t - 1] : 0;
    if (t == 255) bsum[blockIdx.x] = sh[255];
#pragma unroll
    for (int j = 0; j < 4; ++j) {
        int i = base + j;
        if (i < N_SEG) counts[i] = excl;
        excl += v[j];
    }
}

__global__ __launch_bounds__(256) void scan2(int* __restrict__ bsum)
{
    __shared__ int sh[256];
    int t = threadIdx.x;
    sh[t] = (t < SCAN_BLK) ? bsum[t] : 0;
    __syncthreads();
    for (int ofs = 1; ofs < 256; ofs <<= 1) {
        int add = (t >= ofs) ? sh[t - ofs] : 0;
        __syncthreads();
        sh[t] += add;
        __syncthreads();
    }
    int excl = (t > 0) ? sh[t - 1] : 0;
    if (t < SCAN_BLK) bsum[t] = excl;
}

__global__ __launch_bounds__(256) void scan3(
    const int* __restrict__ counts, const int* __restrict__ bsum,
    int* __restrict__ off, int* __restrict__ cursor)
{
    int i = blockIdx.x * 256 + threadIdx.x;
    if (i < N_SEG) {
        int v = counts[i] + bsum[i >> 10];
        off[i] = v;
        cursor[i] = v;
    }
}

__global__ __launch_bounds__(256) void permute_kernel(
    const int* __restrict__ srcA, const int* __restrict__ dstA, const int* __restrict__ typA,
    int* __restrict__ cursor, int* __restrict__ perm)
{
    int e = blockIdx.x * 256 + threadIdx.x;
    if (e < N_EDGES) {
        int pos = atomicAdd(&cursor[typA[e] * N_NODES + dstA[e]], 1);
        perm[pos] = srcA[e];
    }
}

// ---------------- gather-aggregate: one wave per (type,node) segment ----------------
__global__ __launch_bounds__(256) void gather_agg(
    const float* __restrict__ H, const int* __restrict__ perm,
    const int* __restrict__ off, const int* __restrict__ segend,
    float* __restrict__ agg)
{
    int seg = blockIdx.x * 4 + (threadIdx.x >> 6);
    int lane = threadIdx.x & 63;
    if (seg >= N_SEG) return;
    int start = off[seg];
    int end = segend[seg];
    float sx = 0.0f, sy = 0.0f;
    for (int e = start; e < end; ++e) {
        int s = perm[e];
        float2 xv = ((const float2*)(H + (size_t)s * F))[lane];
        sx += xv.x;
        sy += xv.y;
    }
    float sc = 1.0f / fmaxf((float)(end - start), 1.0f);
    ((float2*)(agg + (size_t)seg * F))[lane] = make_float2(sx * sc, sy * sc);
}

// ---------------- MFMA GEMM, bf16x3 split-precision ----------------
// block 256 = 4 waves; tile 64 rows x 128 cols; wave w owns cols [w*32, w*32+32)
// per wave: 4 row-tiles x 2 col-tiles of 16x16 C-frags; K=640 in 20 chunks of 32
__global__ __launch_bounds__(256) void gemm_mfma(
    const float* __restrict__ X,             // [N,F] plane 0
    const float* __restrict__ agg,           // [NT,N,F] pre-scaled means
    const unsigned short* __restrict__ Whsw, // [WELEM] frag-ordered hi (this layer)
    const unsigned short* __restrict__ Wlsw, // [WELEM] frag-ordered lo (this layer)
    const float* __restrict__ bias,          // [F]
    float* __restrict__ out,                 // [N,F]
    int doNormRelu)
{
    __shared__ unsigned short AhS[64][56];   // pitch 56: 16B-aligned frags, ~2-way banks
    __shared__ unsigned short AlS[64][56];
    __shared__ float redb[64][5];
    __shared__ float scl[64];

    const int tid = threadIdx.x;
    const int lane = tid & 63;
    const int w = tid >> 6;
    const int quad = lane >> 4;
    const int l15 = lane & 15;
    const int nodeBase = blockIdx.x * 64;

    f32x4 acc[4][2];
#pragma unroll
    for (int rt = 0; rt < 4; ++rt)
#pragma unroll
        for (int ci = 0; ci < 2; ++ci)
            acc[rt][ci] = (f32x4){0.f, 0.f, 0.f, 0.f};

    const bf16x8* Bh = (const bf16x8*)Whsw;
    const bf16x8* Bl = (const bf16x8*)Wlsw;

    for (int kt = 0; kt < NKT; ++kt) {
        const int p = kt >> 2;               // virtual-A plane
        const int kk0 = (kt & 3) * 32;
        __syncthreads();
        // stage 64 rows x 32 cols of A, converted to bf16 hi/lo
#pragma unroll
        for (int i = 0; i < 2; ++i) {
            int idx = i * 256 + tid;
            int r = idx >> 3;
            int cc = (idx & 7) * 4;
            int n = nodeBase + r;
            int nc = n < N_NODES ? n : N_NODES - 1;
            const float* srcp = (p == 0)
                ? (X + (size_t)nc * F + kk0)
                : (agg + ((size_t)(p - 1) * N_NODES + nc) * F + kk0);
            float4 v = *(const float4*)(srcp + cc);
            ushort4 hi, lo;
            hi.x = f2b(v.x); lo.x = f2b(v.x - b2f(hi.x));
            hi.y = f2b(v.y); lo.y = f2b(v.y - b2f(hi.y));
            hi.z = f2b(v.z); lo.z = f2b(v.z - b2f(hi.z));
            hi.w = f2b(v.w); lo.w = f2b(v.w - b2f(hi.w));
            *(ushort4*)&AhS[r][cc] = hi;
            *(ushort4*)&AlS[r][cc] = lo;
        }
        __syncthreads();

        // B frags (global, L2-resident, coalesced 16B/lane)
        bf16x8 bh[2], bl[2];
#pragma unroll
        for (int ci = 0; ci < 2; ++ci) {
            int fi = (kt * 8 + (w * 2 + ci)) * 64 + lane;
            bh[ci] = Bh[fi];
            bl[ci] = Bl[fi];
        }
        // A frags (LDS)
        bf16x8 ah[4], al[4];
#pragma unroll
        for (int rt = 0; rt < 4; ++rt) {
            int row = rt * 16 + l15;
            ah[rt] = *(const bf16x8*)&AhS[row][quad * 8];
            al[rt] = *(const bf16x8*)&AlS[row][quad * 8];
        }
#pragma unroll
        for (int rt = 0; rt < 4; ++rt)
#pragma unroll
            for (int ci = 0; ci < 2; ++ci) {
                acc[rt][ci] = __builtin_amdgcn_mfma_f32_16x16x32_bf16(ah[rt], bh[ci], acc[rt][ci], 0, 0, 0);
                acc[rt][ci] = __builtin_amdgcn_mfma_f32_16x16x32_bf16(ah[rt], bl[ci], acc[rt][ci], 0, 0, 0);
                acc[rt][ci] = __builtin_amdgcn_mfma_f32_16x16x32_bf16(al[rt], bh[ci], acc[rt][ci], 0, 0, 0);
            }
    }

    // bias (before normalize, per reference)
    float b0 = bias[w * 32 + l15];
    float b1v = bias[w * 32 + 16 + l15];
#pragma unroll
    for (int rt = 0; rt < 4; ++rt)
#pragma unroll
        for (int r = 0; r < 4; ++r) {
            acc[rt][0][r] += b0;
            acc[rt][1][r] += b1v;
        }

    if (doNormRelu) {
#pragma unroll
        for (int rt = 0; rt < 4; ++rt)
#pragma unroll
            for (int r = 0; r < 4; ++r) {
                float v = acc[rt][0][r] * acc[rt][0][r] + acc[rt][1][r] * acc[rt][1][r];
                v += __shfl_xor(v, 1);
                v += __shfl_xor(v, 2);
                v += __shfl_xor(v, 4);
                v += __shfl_xor(v, 8);
                if (l15 == 0) redb[rt * 16 + quad * 4 + r][w] = v;
            }
        __syncthreads();
        if (tid < 64) {
            float s = redb[tid][0] + redb[tid][1] + redb[tid][2] + redb[tid][3];
            scl[tid] = 1.0f / fmaxf(sqrtf(s), 1e-12f);
        }
        __syncthreads();
#pragma unroll
        for (int rt = 0; rt < 4; ++rt)
#pragma unroll
            for (int r = 0; r < 4; ++r) {
                float sc = scl[rt * 16 + quad * 4 + r];
                acc[rt][0][r] = fmaxf(acc[rt][0][r] * sc, 0.0f);
                acc[rt][1][r] = fmaxf(acc[rt][1][r] * sc, 0.0f);
            }
    }

    // store: C/D layout col=lane&15, row=quad*4+reg
#pragma unroll
    for (int rt = 0; rt < 4; ++rt)
#pragma unroll
        for (int r = 0; r < 4; ++r) {
            int row = rt * 16 + quad * 4 + r;
            int n = nodeBase + row;
            if (n < N_NODES) {
                out[(size_t)n * F + w * 32 + l15] = acc[rt][0][r];
                out[(size_t)n * F + w * 32 + 16 + l15] = acc[rt][1][r];
            }
        }
}

extern "C" void kernel_launch(void* const* d_in, const int* in_sizes, int n_in,
                              void* d_out, int out_size, void* d_ws, size_t ws_size,
                              hipStream_t stream)
{
    const float* x   = (const float*)d_in[0];
    const float* Ws1 = (const float*)d_in[1];
    const float* Wn1 = (const float*)d_in[2];
    const float* b1  = (const float*)d_in[3];
    const float* Ws2 = (const float*)d_in[4];
    const float* Wn2 = (const float*)d_in[5];
    const float* b2  = (const float*)d_in[6];
    const int* edge_index = (const int*)d_in[7];
    const int* edge_type  = (const int*)d_in[8];

    const int* srcA = edge_index;
    const int* dstA = edge_index + N_EDGES;

    // workspace layout
    float* ws   = (float*)d_ws;
    float* agg  = ws;                                        // 25,600,000 f
    float* h1   = agg + (size_t)NT * N_NODES * F;            //  6,400,000 f
    float* bavg = h1 + (size_t)N_NODES * F;                  //        256 f
    unsigned short* Whsw = (unsigned short*)(bavg + 2 * F);  // 2*WELEM u16 (16B-aligned)
    unsigned short* Wlsw = Whsw + (size_t)2 * WELEM;         // 2*WELEM u16
    int* counts = (int*)(Wlsw + (size_t)2 * WELEM);          // N_SEG
    int* off    = counts + N_SEG;                            // N_SEG
    int* cursor = off + N_SEG;                               // N_SEG
    int* bsum   = cursor + N_SEG;                            // 256
    int* perm   = bsum + 256;                                // N_EDGES

    // weights: split + swizzle
    {
        int totalThreads = 2 * NKT * 8 * 64 + 2 * F;         // 20736
        hipLaunchKernelGGL(build_w_mfma, dim3((totalThreads + 255) / 256), dim3(256), 0, stream,
                           Ws1, Wn1, b1, Ws2, Wn2, b2, Whsw, Wlsw, bavg);
    }

    // ---------- CSR build (once; shared by both layers) ----------
    hipMemsetAsync(counts, 0, (size_t)N_SEG * sizeof(int), stream);
    hipLaunchKernelGGL(hist_kernel, dim3((N_EDGES + 255) / 256), dim3(256), 0, stream,
                       dstA, edge_type, counts);
    hipLaunchKernelGGL(scan1, dim3(SCAN_BLK), dim3(256), 0, stream, counts, bsum);
    hipLaunchKernelGGL(scan2, dim3(1), dim3(256), 0, stream, bsum);
    hipLaunchKernelGGL(scan3, dim3((N_SEG + 255) / 256), dim3(256), 0, stream,
                       counts, bsum, off, cursor);
    hipLaunchKernelGGL(permute_kernel, dim3((N_EDGES + 255) / 256), dim3(256), 0, stream,
                       srcA, dstA, edge_type, cursor, perm);
    // off[seg] = start, cursor[seg] = end

    // ---------- layer 1 ----------
    hipLaunchKernelGGL(gather_agg, dim3(N_SEG / 4), dim3(256), 0, stream,
                       x, perm, off, cursor, agg);
    hipLaunchKernelGGL(gemm_mfma, dim3((N_NODES + 63) / 64), dim3(256), 0, stream,
                       x, agg, Whsw, Wlsw, bavg, h1, 1);

    // ---------- layer 2 ----------
    hipLaunchKernelGGL(gather_agg, dim3(N_SEG / 4), dim3(256), 0, stream,
                       h1, perm, off, cursor, agg);
    hipLaunchKernelGGL(gemm_mfma, dim3((N_NODES + 63) / 64), dim3(256), 0, stream,
                       h1, agg, Whsw + WELEM, Wlsw + WELEM, bavg + F, (float*)d_out, 0);
}